// Round 1
// baseline (52.305 us; speedup 1.0000x reference)
//
#include <hip/hip_runtime.h>

#define NN 512
#define AA 512
#define BB 32
#define CC 16
#define BC (BB * CC)      // 512
#define OUTW (AA + BB)    // 544

constexpr int GROWS = 4;  // M rows per block in gemm kernel
constexpr int ITILE = 4;  // i values per block in pairwise kernel

// M = x @ T.reshape(A, B*C); also copy x into out[:, 0:A]
__global__ __launch_bounds__(512) void gemm_kernel(const float* __restrict__ x,
                                                   const float* __restrict__ T,
                                                   float* __restrict__ M,
                                                   float* __restrict__ out) {
    const int i0 = blockIdx.x * GROWS;
    const int t  = threadIdx.x;  // output column 0..511

    __shared__ float xs[GROWS][128];
    float acc[GROWS];
#pragma unroll
    for (int r = 0; r < GROWS; ++r) acc[r] = 0.f;

    for (int k0 = 0; k0 < AA; k0 += 128) {
        __syncthreads();
        {
            const int r  = t >> 7;    // 0..3
            const int kk = t & 127;
            xs[r][kk] = x[(size_t)(i0 + r) * AA + k0 + kk];
        }
        __syncthreads();
#pragma unroll 8
        for (int kk = 0; kk < 128; ++kk) {
            const float tv = T[(size_t)(k0 + kk) * BC + t];
#pragma unroll
            for (int r = 0; r < GROWS; ++r) acc[r] = fmaf(xs[r][kk], tv, acc[r]);
        }
    }

#pragma unroll
    for (int r = 0; r < GROWS; ++r) M[(size_t)(i0 + r) * BC + t] = acc[r];
    // copy x rows into the first AA columns of out
#pragma unroll
    for (int r = 0; r < GROWS; ++r) out[(size_t)(i0 + r) * OUTW + t] = x[(size_t)(i0 + r) * AA + t];
}

// out[i, A+b] = sum_j exp(-sum_c |M[i,b,c]-M[j,b,c]|) - 1
__global__ __launch_bounds__(512) void pairwise_kernel(const float* __restrict__ M,
                                                       float* __restrict__ out) {
    const int i0 = blockIdx.x * ITILE;
    const int t  = threadIdx.x;
    const int b  = t & 31;   // feature block 0..31
    const int jg = t >> 5;   // j group 0..15

    // load M[i0+r, b, 0:16] into registers
    float mi[ITILE][CC];
#pragma unroll
    for (int r = 0; r < ITILE; ++r) {
        const float4* p = (const float4*)(M + (size_t)(i0 + r) * BC + b * CC);
        const float4 v0 = p[0], v1 = p[1], v2 = p[2], v3 = p[3];
        mi[r][0] = v0.x;  mi[r][1] = v0.y;  mi[r][2] = v0.z;  mi[r][3] = v0.w;
        mi[r][4] = v1.x;  mi[r][5] = v1.y;  mi[r][6] = v1.z;  mi[r][7] = v1.w;
        mi[r][8] = v2.x;  mi[r][9] = v2.y;  mi[r][10] = v2.z; mi[r][11] = v2.w;
        mi[r][12] = v3.x; mi[r][13] = v3.y; mi[r][14] = v3.z; mi[r][15] = v3.w;
    }

    float acc[ITILE];
#pragma unroll
    for (int r = 0; r < ITILE; ++r) acc[r] = 0.f;

    for (int jj = 0; jj < 32; ++jj) {
        const int j = (jg << 5) + jj;
        const float4* p = (const float4*)(M + (size_t)j * BC + b * CC);
        const float4 m0 = p[0], m1 = p[1], m2 = p[2], m3 = p[3];
        float mj[CC] = {m0.x, m0.y, m0.z, m0.w, m1.x, m1.y, m1.z, m1.w,
                        m2.x, m2.y, m2.z, m2.w, m3.x, m3.y, m3.z, m3.w};
#pragma unroll
        for (int r = 0; r < ITILE; ++r) {
            float d0 = 0.f, d1 = 0.f, d2 = 0.f, d3 = 0.f;
#pragma unroll
            for (int c = 0; c < CC; c += 4) {
                d0 += fabsf(mj[c + 0] - mi[r][c + 0]);
                d1 += fabsf(mj[c + 1] - mi[r][c + 1]);
                d2 += fabsf(mj[c + 2] - mi[r][c + 2]);
                d3 += fabsf(mj[c + 3] - mi[r][c + 3]);
            }
            const float d = (d0 + d1) + (d2 + d3);
            acc[r] += __expf(-d);
        }
    }

    // reduce the 16 j-group partials per (r, b)
    __shared__ float red[ITILE][16][32];
#pragma unroll
    for (int r = 0; r < ITILE; ++r) red[r][jg][b] = acc[r];
    __syncthreads();

    if (t < 32 * ITILE) {
        const int b2 = t & 31;
        const int r  = t >> 5;
        float s = 0.f;
#pragma unroll
        for (int g = 0; g < 16; ++g) s += red[r][g][b2];
        // the -1.0 cancels the j==i self term exp(0)=1
        out[(size_t)(i0 + r) * OUTW + AA + b2] = s - 1.0f;
    }
}

extern "C" void kernel_launch(void* const* d_in, const int* in_sizes, int n_in,
                              void* d_out, int out_size, void* d_ws, size_t ws_size,
                              hipStream_t stream) {
    const float* x = (const float*)d_in[0];  // (N, A)
    const float* T = (const float*)d_in[1];  // (A, B, C)
    float* out = (float*)d_out;              // (N, A+B)
    float* M   = (float*)d_ws;               // (N, B*C) scratch, 1 MiB

    gemm_kernel<<<NN / GROWS, 512, 0, stream>>>(x, T, M, out);
    pairwise_kernel<<<NN / ITILE, 512, 0, stream>>>(M, out);
}

// Round 2
// 37.802 us; speedup vs baseline: 1.3836x; 1.3836x over previous
//
#include <hip/hip_runtime.h>

#define NN 512
#define AA 512
#define BB 32
#define CC 16
#define BC (BB * CC)      // 512
#define OUTW (AA + BB)    // 544

constexpr int GROWS  = 4;    // M rows per block in gemm kernel
constexpr int ITILE  = 4;    // i values per block in pairwise kernel
constexpr int NJC    = 4;    // j-chunks
constexpr int JCHUNK = NN / NJC;  // 128

// M = x @ T.reshape(A, B*C); also copy x into out[:, 0:A]
__global__ __launch_bounds__(512) void gemm_kernel(const float* __restrict__ x,
                                                   const float* __restrict__ T,
                                                   float* __restrict__ M,
                                                   float* __restrict__ out) {
    const int i0 = blockIdx.x * GROWS;
    const int t  = threadIdx.x;  // output column 0..511

    __shared__ float xs[GROWS][128];
    float acc[GROWS];
#pragma unroll
    for (int r = 0; r < GROWS; ++r) acc[r] = 0.f;

    for (int k0 = 0; k0 < AA; k0 += 128) {
        __syncthreads();
        {
            const int r  = t >> 7;    // 0..3
            const int kk = t & 127;
            xs[r][kk] = x[(size_t)(i0 + r) * AA + k0 + kk];
        }
        __syncthreads();
#pragma unroll 8
        for (int kk = 0; kk < 128; ++kk) {
            const float tv = T[(size_t)(k0 + kk) * BC + t];
#pragma unroll
            for (int r = 0; r < GROWS; ++r) acc[r] = fmaf(xs[r][kk], tv, acc[r]);
        }
    }

#pragma unroll
    for (int r = 0; r < GROWS; ++r) M[(size_t)(i0 + r) * BC + t] = acc[r];
#pragma unroll
    for (int r = 0; r < GROWS; ++r) out[(size_t)(i0 + r) * OUTW + t] = x[(size_t)(i0 + r) * AA + t];
}

// part[jc][i][b] = sum_{j in chunk jc} exp(-sum_c |M[i,b,c]-M[j,b,c]|)
__global__ __launch_bounds__(512) void pairwise_kernel(const float* __restrict__ M,
                                                       float* __restrict__ part) {
    const int i0 = blockIdx.x * ITILE;
    const int jc = blockIdx.y;
    const int t  = threadIdx.x;
    const int b  = t & 31;   // feature block 0..31
    const int jg = t >> 5;   // j group 0..15

    float mi[ITILE][CC];
#pragma unroll
    for (int r = 0; r < ITILE; ++r) {
        const float4* p = (const float4*)(M + (size_t)(i0 + r) * BC + b * CC);
        const float4 v0 = p[0], v1 = p[1], v2 = p[2], v3 = p[3];
        mi[r][0] = v0.x;  mi[r][1] = v0.y;  mi[r][2] = v0.z;  mi[r][3] = v0.w;
        mi[r][4] = v1.x;  mi[r][5] = v1.y;  mi[r][6] = v1.z;  mi[r][7] = v1.w;
        mi[r][8] = v2.x;  mi[r][9] = v2.y;  mi[r][10] = v2.z; mi[r][11] = v2.w;
        mi[r][12] = v3.x; mi[r][13] = v3.y; mi[r][14] = v3.z; mi[r][15] = v3.w;
    }

    float acc[ITILE];
#pragma unroll
    for (int r = 0; r < ITILE; ++r) acc[r] = 0.f;

    const int jbase = jc * JCHUNK + jg * (JCHUNK / 16);
#pragma unroll
    for (int jj = 0; jj < JCHUNK / 16; ++jj) {   // 8 iterations
        const int j = jbase + jj;
        const float4* p = (const float4*)(M + (size_t)j * BC + b * CC);
        const float4 m0 = p[0], m1 = p[1], m2 = p[2], m3 = p[3];
        float mj[CC] = {m0.x, m0.y, m0.z, m0.w, m1.x, m1.y, m1.z, m1.w,
                        m2.x, m2.y, m2.z, m2.w, m3.x, m3.y, m3.z, m3.w};
#pragma unroll
        for (int r = 0; r < ITILE; ++r) {
            float d0 = 0.f, d1 = 0.f, d2 = 0.f, d3 = 0.f;
#pragma unroll
            for (int c = 0; c < CC; c += 4) {
                d0 += fabsf(mj[c + 0] - mi[r][c + 0]);
                d1 += fabsf(mj[c + 1] - mi[r][c + 1]);
                d2 += fabsf(mj[c + 2] - mi[r][c + 2]);
                d3 += fabsf(mj[c + 3] - mi[r][c + 3]);
            }
            const float d = (d0 + d1) + (d2 + d3);
            acc[r] += __expf(-d);
        }
    }

    __shared__ float red[ITILE][16][32];
#pragma unroll
    for (int r = 0; r < ITILE; ++r) red[r][jg][b] = acc[r];
    __syncthreads();

    if (t < 32 * ITILE) {
        const int b2 = t & 31;
        const int r  = t >> 5;
        float s = 0.f;
#pragma unroll
        for (int g = 0; g < 16; ++g) s += red[r][g][b2];
        part[((size_t)jc * NN + (i0 + r)) * BB + b2] = s;
    }
}

// out[i, A+b] = sum_jc part[jc][i][b] - 1
__global__ __launch_bounds__(256) void reduce_kernel(const float* __restrict__ part,
                                                     float* __restrict__ out) {
    const int idx = blockIdx.x * 256 + threadIdx.x;  // 0 .. 512*32-1
    const int i = idx >> 5;
    const int b = idx & 31;
    float s = 0.f;
#pragma unroll
    for (int jc = 0; jc < NJC; ++jc) s += part[((size_t)jc * NN + i) * BB + b];
    out[(size_t)i * OUTW + AA + b] = s - 1.0f;
}

extern "C" void kernel_launch(void* const* d_in, const int* in_sizes, int n_in,
                              void* d_out, int out_size, void* d_ws, size_t ws_size,
                              hipStream_t stream) {
    const float* x = (const float*)d_in[0];  // (N, A)
    const float* T = (const float*)d_in[1];  // (A, B, C)
    float* out  = (float*)d_out;             // (N, A+B)
    float* M    = (float*)d_ws;              // (N, B*C) scratch, 1 MiB
    float* part = (float*)d_ws + (size_t)NN * BC;  // (NJC, N, B), 256 KiB

    gemm_kernel<<<NN / GROWS, 512, 0, stream>>>(x, T, M, out);
    pairwise_kernel<<<dim3(NN / ITILE, NJC), 512, 0, stream>>>(M, part);
    reduce_kernel<<<(NN * BB) / 256, 256, 0, stream>>>(part, out);
}

// Round 3
// 26.962 us; speedup vs baseline: 1.9400x; 1.4021x over previous
//
#include <hip/hip_runtime.h>

#define NN 512
#define AA 512
#define BB 32
#define CC 16
#define BC 512            // B*C
#define OUTW 544          // A+B
#define LOG2E 1.44269504088896340736f

// ---------------- gemm: M = (x @ T) * log2(e); also out[:, :A] = x, out[:, A:] = -1
// grid: 512 blocks = 64 row-groups x 8 col-groups; block: 8 rows x 64 cols, k split 8 ways
constexpr int G_ROWS = 8;
constexpr int G_COLS = 64;
constexpr int G_KSPL = 8;
constexpr int G_KLEN = AA / G_KSPL;  // 64

__global__ __launch_bounds__(512) void gemm_kernel(const float* __restrict__ x,
                                                   const float* __restrict__ T,
                                                   float* __restrict__ M,
                                                   float* __restrict__ out) {
    const int bx = blockIdx.x;
    const int i0 = (bx >> 3) * G_ROWS;
    const int c0 = (bx & 7) * G_COLS;
    const int t  = threadIdx.x;
    const int kq = t >> 6;   // 0..7 k-split
    const int c  = t & 63;   // col within tile

    __shared__ float xsT[AA][G_ROWS];                    // transposed x tile, 16 KB
    __shared__ float red[G_KSPL][G_COLS][G_ROWS + 1];    // padded partials, ~18 KB

    // cooperative fill: 8 rows x 512 k, 8 floats/thread, rows interleaved across lanes
    {
        const int r  = t & 7;
        const int k0 = (t >> 3) * 8;
        const float4 v0 = *(const float4*)(x + (size_t)(i0 + r) * AA + k0);
        const float4 v1 = *(const float4*)(x + (size_t)(i0 + r) * AA + k0 + 4);
        xsT[k0 + 0][r] = v0.x; xsT[k0 + 1][r] = v0.y;
        xsT[k0 + 2][r] = v0.z; xsT[k0 + 3][r] = v0.w;
        xsT[k0 + 4][r] = v1.x; xsT[k0 + 5][r] = v1.y;
        xsT[k0 + 6][r] = v1.z; xsT[k0 + 7][r] = v1.w;
    }
    __syncthreads();

    float acc[G_ROWS];
#pragma unroll
    for (int r = 0; r < G_ROWS; ++r) acc[r] = 0.f;

    const float* Tp = T + (size_t)(kq * G_KLEN) * BC + c0 + c;
#pragma unroll 8
    for (int kk = 0; kk < G_KLEN; ++kk) {
        const float tv = Tp[(size_t)kk * BC];
        const int k = kq * G_KLEN + kk;
        const float4 xa = *(const float4*)&xsT[k][0];   // broadcast ds_read_b128
        const float4 xb = *(const float4*)&xsT[k][4];
        acc[0] = fmaf(xa.x, tv, acc[0]);
        acc[1] = fmaf(xa.y, tv, acc[1]);
        acc[2] = fmaf(xa.z, tv, acc[2]);
        acc[3] = fmaf(xa.w, tv, acc[3]);
        acc[4] = fmaf(xb.x, tv, acc[4]);
        acc[5] = fmaf(xb.y, tv, acc[5]);
        acc[6] = fmaf(xb.z, tv, acc[6]);
        acc[7] = fmaf(xb.w, tv, acc[7]);
    }

#pragma unroll
    for (int r = 0; r < G_ROWS; ++r) red[kq][c][r] = acc[r];
    __syncthreads();

    // combine 8 k-split partials: 512 outputs, 1 per thread
    {
        const int r  = t >> 6;
        const int cc = t & 63;
        float s = 0.f;
#pragma unroll
        for (int q = 0; q < G_KSPL; ++q) s += red[q][cc][r];
        M[(size_t)(i0 + r) * BC + c0 + cc] = s * LOG2E;  // pre-scale for exp2
        out[(size_t)(i0 + r) * OUTW + c0 + cc] = x[(size_t)(i0 + r) * AA + c0 + cc];
    }
    // init out[:, A:] = -1 (rewritten every call; cancels the j==i self-term)
    if ((bx & 7) == 0 && t < G_ROWS * BB) {
        out[(size_t)(i0 + (t >> 5)) * OUTW + AA + (t & 31)] = -1.0f;
    }
}

// ---------------- pairwise: out[i, A+b] += sum_{j in chunk} exp2(-sum_c |M[i,b,c]-M[j,b,c]|)
constexpr int ITILE  = 4;
constexpr int NJC    = 4;
constexpr int JCHUNK = NN / NJC;  // 128

__global__ __launch_bounds__(512) void pairwise_kernel(const float* __restrict__ M,
                                                       float* __restrict__ out) {
    const int i0 = blockIdx.x * ITILE;
    const int jc = blockIdx.y;
    const int t  = threadIdx.x;
    const int b  = t & 31;   // feature block 0..31
    const int jg = t >> 5;   // j group 0..15

    float mi[ITILE][CC];
#pragma unroll
    for (int r = 0; r < ITILE; ++r) {
        const float4* p = (const float4*)(M + (size_t)(i0 + r) * BC + b * CC);
        const float4 v0 = p[0], v1 = p[1], v2 = p[2], v3 = p[3];
        mi[r][0] = v0.x;  mi[r][1] = v0.y;  mi[r][2] = v0.z;  mi[r][3] = v0.w;
        mi[r][4] = v1.x;  mi[r][5] = v1.y;  mi[r][6] = v1.z;  mi[r][7] = v1.w;
        mi[r][8] = v2.x;  mi[r][9] = v2.y;  mi[r][10] = v2.z; mi[r][11] = v2.w;
        mi[r][12] = v3.x; mi[r][13] = v3.y; mi[r][14] = v3.z; mi[r][15] = v3.w;
    }

    float acc[ITILE];
#pragma unroll
    for (int r = 0; r < ITILE; ++r) acc[r] = 0.f;

    const int jbase = jc * JCHUNK + jg * (JCHUNK / 16);
#pragma unroll
    for (int jj = 0; jj < JCHUNK / 16; ++jj) {   // 8 iterations, fully unrolled
        const int j = jbase + jj;
        const float4* p = (const float4*)(M + (size_t)j * BC + b * CC);
        const float4 m0 = p[0], m1 = p[1], m2 = p[2], m3 = p[3];
        float mj[CC] = {m0.x, m0.y, m0.z, m0.w, m1.x, m1.y, m1.z, m1.w,
                        m2.x, m2.y, m2.z, m2.w, m3.x, m3.y, m3.z, m3.w};
#pragma unroll
        for (int r = 0; r < ITILE; ++r) {
            float d0 = 0.f, d1 = 0.f, d2 = 0.f, d3 = 0.f;
#pragma unroll
            for (int c = 0; c < CC; c += 4) {
                d0 += fabsf(mj[c + 0] - mi[r][c + 0]);
                d1 += fabsf(mj[c + 1] - mi[r][c + 1]);
                d2 += fabsf(mj[c + 2] - mi[r][c + 2]);
                d3 += fabsf(mj[c + 3] - mi[r][c + 3]);
            }
            const float d = (d0 + d1) + (d2 + d3);
            acc[r] += __builtin_amdgcn_exp2f(-d);   // M pre-scaled by log2(e)
        }
    }

    __shared__ float red[ITILE][16][32];
#pragma unroll
    for (int r = 0; r < ITILE; ++r) red[r][jg][b] = acc[r];
    __syncthreads();

    if (t < 32 * ITILE) {
        const int b2 = t & 31;
        const int r  = t >> 5;
        float s = 0.f;
#pragma unroll
        for (int g = 0; g < 16; ++g) s += red[r][g][b2];
        atomicAdd(out + (size_t)(i0 + r) * OUTW + AA + b2, s);
    }
}

extern "C" void kernel_launch(void* const* d_in, const int* in_sizes, int n_in,
                              void* d_out, int out_size, void* d_ws, size_t ws_size,
                              hipStream_t stream) {
    const float* x = (const float*)d_in[0];  // (N, A)
    const float* T = (const float*)d_in[1];  // (A, B, C)
    float* out = (float*)d_out;              // (N, A+B)
    float* M   = (float*)d_ws;               // (N, B*C) scratch, 1 MiB

    gemm_kernel<<<512, 512, 0, stream>>>(x, T, M, out);
    pairwise_kernel<<<dim3(NN / ITILE, NJC), 512, 0, stream>>>(M, out);
}